// Round 2
// baseline (47.155 us; speedup 1.0000x reference)
//
#include <hip/hip_runtime.h>
#include <math.h>

#define HW2   196      // 14*14
#define IMG   224
#define IMG2  (224*224)
#define NBLK1 512

// ---------------- K1: 16x16 patch means -> resized[B*196], + block partials ----
// Grid-stride over groups of 4 patches; one wave (64 lanes) per patch.
// Lane = row*4 + c4, each lane loads float4 (64B/row/wave segments).
__global__ __launch_bounds__(256) void k_patch_mean(const float* __restrict__ in,
                                                    float* __restrict__ resized,
                                                    float* __restrict__ pmin,
                                                    float* __restrict__ pmax,
                                                    double* __restrict__ psum,
                                                    int npair) {
    int wid  = threadIdx.x >> 6;
    int lane = threadIdx.x & 63;
    int row  = lane >> 2;
    int c4   = lane & 3;
    int ngroups = (npair + 3) / 4;

    float  mn = INFINITY, mx = -INFINITY;
    double sm = 0.0;

    for (int g = blockIdx.x; g < ngroups; g += gridDim.x) {
        int p = g * 4 + wid;
        if (p < npair) {
            int b   = p / HW2;
            int rem = p - b * HW2;
            int py  = rem / 14;
            int px  = rem - py * 14;
            const float4* src = (const float4*)(in + (size_t)b * IMG2
                                                  + (size_t)(py * 16 + row) * IMG
                                                  + px * 16) + c4;
            float4 v = *src;
            double s = (double)v.x + (double)v.y + (double)v.z + (double)v.w;
            #pragma unroll
            for (int off = 32; off; off >>= 1) s += __shfl_xor(s, off, 64);
            if (lane == 0) {
                float mean = (float)(s * (1.0 / 256.0));
                resized[p] = mean;
                mn = fminf(mn, mean);
                mx = fmaxf(mx, mean);
                sm += (double)mean;
            }
        }
    }

    __shared__ float  smn[4], smx[4];
    __shared__ double ssm[4];
    if (lane == 0) { smn[wid] = mn; smx[wid] = mx; ssm[wid] = sm; }
    __syncthreads();
    if (threadIdx.x == 0) {
        pmin[blockIdx.x] = fminf(fminf(smn[0], smn[1]), fminf(smn[2], smn[3]));
        pmax[blockIdx.x] = fmaxf(fmaxf(smx[0], smx[1]), fmaxf(smx[2], smx[3]));
        psum[blockIdx.x] = ssm[0] + ssm[1] + ssm[2] + ssm[3];
    }
}

// ---------------- K2: redundant scalar reduce + ratio / importance / mask -------
__global__ __launch_bounds__(256) void k_output(const float* __restrict__ resized,
                                                const float* __restrict__ pmin,
                                                const float* __restrict__ pmax,
                                                const double* __restrict__ psum,
                                                int nblk1,
                                                float* __restrict__ out,
                                                int npair, int tpp, int num_tokens) {
    // --- redundant reduction of partials (fixed order -> deterministic,
    //     identical in every block) ---
    int t = threadIdx.x;
    float  mn = INFINITY, mx = -INFINITY;
    double s  = 0.0;
    for (int i = t; i < nblk1; i += 256) {
        mn = fminf(mn, pmin[i]);
        mx = fmaxf(mx, pmax[i]);
        s += psum[i];
    }
    #pragma unroll
    for (int off = 32; off; off >>= 1) {
        mn = fminf(mn, __shfl_xor(mn, off, 64));
        mx = fmaxf(mx, __shfl_xor(mx, off, 64));
        s += __shfl_xor(s, off, 64);
    }
    __shared__ float  smn[4], smx[4];
    __shared__ double ssm[4];
    __shared__ float  sc3[3];
    int wid = t >> 6, lane = t & 63;
    if (lane == 0) { smn[wid] = mn; smx[wid] = mx; ssm[wid] = s; }
    __syncthreads();
    if (t == 0) {
        mn = fminf(fminf(smn[0], smn[1]), fminf(smn[2], smn[3]));
        mx = fmaxf(fmaxf(smx[0], smx[1]), fmaxf(smx[2], smx[3]));
        s  = ssm[0] + ssm[1] + ssm[2] + ssm[3];
        // reference f32 semantics: denom = (m_max - m_min) + 1e-6 in f32
        float denom = __fadd_rn(__fsub_rn(mx, mn), 1e-6f);
        double mean     = s / (double)npair;
        double avg_norm = (mean - (double)mn) / (double)denom;
        double cur_avg  = 0.25 + 0.75 * avg_norm;          // mean of compression_ratio
        sc3[0] = mn;
        sc3[1] = denom;
        sc3[2] = (float)(0.5 / (cur_avg + 1e-6));
    }
    __syncthreads();
    float fmn = sc3[0], fden = sc3[1], fscale = sc3[2];

    // --- per-pair outputs ---
    int base = blockIdx.x * 256;
    int g = base + t;
    __shared__ int      kk[256];
    __shared__ unsigned kbase[256];   // element offset of this pair's mask row
    int k = 0;
    unsigned kb = 0;
    if (g < npair) {
        float r = resized[g];
        // emulate np elementwise f32 rounding: no fma contraction
        float norm   = __fdiv_rn(__fsub_rn(r, fmn), fden);
        float ratio0 = __fadd_rn(0.25f, __fmul_rn(0.75f, norm));
        float sc     = __fmul_rn(ratio0, fscale);
        float ratio  = fminf(fmaxf(sc, 0.25f), 1.0f);
        k = (int)rintf(__fmul_rn(ratio, (float)tpp));   // jnp.round = half-to-even
        k = min(max(k, 1), tpp);
        out[g]         = ratio;   // compression_ratio
        out[npair + g] = norm;    // importance_scores
        unsigned b = (unsigned)g / HW2;
        unsigned p = (unsigned)g - b * HW2;
        kb = b * (unsigned)num_tokens + p * (unsigned)tpp;
    }
    kk[t]    = k;
    kbase[t] = kb;
    __syncthreads();

    float* mask = out + 2 * (size_t)npair;
    int nprs = min(256, npair - base);
    if ((tpp & 3) == 0) {
        int tq = tpp >> 2;
        int total4 = nprs * tq;
        for (int i = t; i < total4; i += 256) {
            int pr = (unsigned)i / (unsigned)tq;
            int wi = (i - pr * tq) * 4;
            int kv = kk[pr];
            float4 m;
            m.x = (wi     < kv) ? 1.0f : 0.0f;
            m.y = (wi + 1 < kv) ? 1.0f : 0.0f;
            m.z = (wi + 2 < kv) ? 1.0f : 0.0f;
            m.w = (wi + 3 < kv) ? 1.0f : 0.0f;
            *(float4*)(mask + (size_t)kbase[pr] + wi) = m;
        }
    } else {
        int total = nprs * tpp;
        for (int i = t; i < total; i += 256) {
            int pr = (unsigned)i / (unsigned)tpp;
            int wi = i - pr * tpp;
            mask[(size_t)kbase[pr] + wi] = (wi < kk[pr]) ? 1.0f : 0.0f;
        }
    }
}

// ---------------- pad (only if 196*tpp < num_tokens; not hit at these sizes) ----
__global__ void k_pad(float* __restrict__ mask, int B, int num_tokens, int used) {
    int per = num_tokens - used;
    int idx = blockIdx.x * 256 + threadIdx.x;
    int tot = B * per;
    if (idx < tot) {
        int b = idx / per;
        int j = idx - b * per;
        mask[(size_t)b * num_tokens + used + j] = 0.0f;
    }
}

extern "C" void kernel_launch(void* const* d_in, const int* in_sizes, int n_in,
                              void* d_out, int out_size, void* d_ws, size_t ws_size,
                              hipStream_t stream) {
    const float* motion = (const float*)d_in[0];
    int nelem = in_sizes[0];                 // B*1*224*224
    int B     = nelem / IMG2;                // 512
    int npair = B * HW2;                     // 100352
    int num_tokens = (out_size - 2 * npair) / B;   // 6272
    int tpp   = num_tokens / HW2;            // 32

    // workspace layout
    float* resized = (float*)d_ws;
    size_t off = ((size_t)npair * sizeof(float) + 7) & ~(size_t)7;
    double* psum = (double*)((char*)d_ws + off);
    float*  pmin = (float*)(psum + NBLK1);
    float*  pmax = pmin + NBLK1;

    int ngroups = (npair + 3) / 4;
    int nb1 = min(NBLK1, ngroups);
    hipLaunchKernelGGL(k_patch_mean, dim3(nb1), dim3(256), 0, stream,
                       motion, resized, pmin, pmax, psum, npair);

    int nb2 = (npair + 255) / 256;           // 392
    hipLaunchKernelGGL(k_output, dim3(nb2), dim3(256), 0, stream,
                       resized, pmin, pmax, psum, nb1,
                       (float*)d_out, npair, tpp, num_tokens);

    int used = HW2 * tpp;
    if (used < num_tokens) {
        int tot = B * (num_tokens - used);
        hipLaunchKernelGGL(k_pad, dim3((tot + 255) / 256), dim3(256), 0, stream,
                           (float*)d_out + 2 * (size_t)npair, B, num_tokens, used);
    }
}

// Round 3
// 31.246 us; speedup vs baseline: 1.5091x; 1.5091x over previous
//
#include <hip/hip_runtime.h>
#include <math.h>

#define HW2   196      // 14*14
#define IMG   224
#define IMG2  (224*224)
#define NBLK1 3584     // 25088 groups / 7 per block; 14 blocks/CU

// ---------------- K1: 16x16 patch means -> resized[B*196], + block partials ----
// Grid-stride over groups of 4 patches; one wave (64 lanes) per patch.
// Lane = row*4 + c4, each lane loads float4 (64B/row/wave segments).
__global__ __launch_bounds__(256) void k_patch_mean(const float* __restrict__ in,
                                                    float* __restrict__ resized,
                                                    float* __restrict__ pmin,
                                                    float* __restrict__ pmax,
                                                    double* __restrict__ psum,
                                                    int npair) {
    int wid  = threadIdx.x >> 6;
    int lane = threadIdx.x & 63;
    int row  = lane >> 2;
    int c4   = lane & 3;
    int ngroups = (npair + 3) / 4;

    float  mn = INFINITY, mx = -INFINITY;
    double sm = 0.0;

    for (int g = blockIdx.x; g < ngroups; g += gridDim.x) {
        int p = g * 4 + wid;
        if (p < npair) {
            int b   = p / HW2;
            int rem = p - b * HW2;
            int py  = rem / 14;
            int px  = rem - py * 14;
            const float4* src = (const float4*)(in + (size_t)b * IMG2
                                                  + (size_t)(py * 16 + row) * IMG
                                                  + px * 16) + c4;
            float4 v = *src;
            // f32 in-patch reduce (error ~1e-5 << 2e-2 threshold); f64 only
            // for the cross-patch running sum.
            float s = (v.x + v.y) + (v.z + v.w);
            #pragma unroll
            for (int off = 32; off; off >>= 1) s += __shfl_xor(s, off, 64);
            if (lane == 0) {
                float mean = s * (1.0f / 256.0f);
                resized[p] = mean;
                mn = fminf(mn, mean);
                mx = fmaxf(mx, mean);
                sm += (double)mean;
            }
        }
    }

    __shared__ float  smn[4], smx[4];
    __shared__ double ssm[4];
    if (lane == 0) { smn[wid] = mn; smx[wid] = mx; ssm[wid] = sm; }
    __syncthreads();
    if (threadIdx.x == 0) {
        pmin[blockIdx.x] = fminf(fminf(smn[0], smn[1]), fminf(smn[2], smn[3]));
        pmax[blockIdx.x] = fmaxf(fmaxf(smx[0], smx[1]), fmaxf(smx[2], smx[3]));
        psum[blockIdx.x] = ssm[0] + ssm[1] + ssm[2] + ssm[3];
    }
}

// ---------------- K2: redundant scalar reduce + ratio / importance / mask -------
__global__ __launch_bounds__(256) void k_output(const float* __restrict__ resized,
                                                const float* __restrict__ pmin,
                                                const float* __restrict__ pmax,
                                                const double* __restrict__ psum,
                                                int nblk1,
                                                float* __restrict__ out,
                                                int npair, int tpp, int num_tokens) {
    // --- redundant reduction of partials (fixed order -> deterministic,
    //     identical in every block; partials are L2-resident) ---
    int t = threadIdx.x;
    float  mn = INFINITY, mx = -INFINITY;
    double s  = 0.0;
    for (int i = t; i < nblk1; i += 256) {
        mn = fminf(mn, pmin[i]);
        mx = fmaxf(mx, pmax[i]);
        s += psum[i];
    }
    #pragma unroll
    for (int off = 32; off; off >>= 1) {
        mn = fminf(mn, __shfl_xor(mn, off, 64));
        mx = fmaxf(mx, __shfl_xor(mx, off, 64));
        s += __shfl_xor(s, off, 64);
    }
    __shared__ float  smn[4], smx[4];
    __shared__ double ssm[4];
    __shared__ float  sc3[3];
    int wid = t >> 6, lane = t & 63;
    if (lane == 0) { smn[wid] = mn; smx[wid] = mx; ssm[wid] = s; }
    __syncthreads();
    if (t == 0) {
        mn = fminf(fminf(smn[0], smn[1]), fminf(smn[2], smn[3]));
        mx = fmaxf(fmaxf(smx[0], smx[1]), fmaxf(smx[2], smx[3]));
        s  = ssm[0] + ssm[1] + ssm[2] + ssm[3];
        // reference f32 semantics: denom = (m_max - m_min) + 1e-6 in f32
        float denom = __fadd_rn(__fsub_rn(mx, mn), 1e-6f);
        double mean     = s / (double)npair;
        double avg_norm = (mean - (double)mn) / (double)denom;
        double cur_avg  = 0.25 + 0.75 * avg_norm;          // mean of compression_ratio
        sc3[0] = mn;
        sc3[1] = denom;
        sc3[2] = (float)(0.5 / (cur_avg + 1e-6));
    }
    __syncthreads();
    float fmn = sc3[0], fden = sc3[1], fscale = sc3[2];

    // --- per-pair outputs ---
    int base = blockIdx.x * 256;
    int g = base + t;
    __shared__ int      kk[256];
    __shared__ unsigned kbase[256];   // element offset of this pair's mask row
    int k = 0;
    unsigned kb = 0;
    if (g < npair) {
        float r = resized[g];
        // emulate np elementwise f32 rounding: no fma contraction
        float norm   = __fdiv_rn(__fsub_rn(r, fmn), fden);
        float ratio0 = __fadd_rn(0.25f, __fmul_rn(0.75f, norm));
        float sc     = __fmul_rn(ratio0, fscale);
        float ratio  = fminf(fmaxf(sc, 0.25f), 1.0f);
        k = (int)rintf(__fmul_rn(ratio, (float)tpp));   // jnp.round = half-to-even
        k = min(max(k, 1), tpp);
        out[g]         = ratio;   // compression_ratio
        out[npair + g] = norm;    // importance_scores
        unsigned b = (unsigned)g / HW2;
        unsigned p = (unsigned)g - b * HW2;
        kb = b * (unsigned)num_tokens + p * (unsigned)tpp;
    }
    kk[t]    = k;
    kbase[t] = kb;
    __syncthreads();

    float* mask = out + 2 * (size_t)npair;
    int nprs = min(256, npair - base);
    if ((tpp & 3) == 0) {
        int tq = tpp >> 2;
        int total4 = nprs * tq;
        for (int i = t; i < total4; i += 256) {
            int pr = (unsigned)i / (unsigned)tq;
            int wi = (i - pr * tq) * 4;
            int kv = kk[pr];
            float4 m;
            m.x = (wi     < kv) ? 1.0f : 0.0f;
            m.y = (wi + 1 < kv) ? 1.0f : 0.0f;
            m.z = (wi + 2 < kv) ? 1.0f : 0.0f;
            m.w = (wi + 3 < kv) ? 1.0f : 0.0f;
            *(float4*)(mask + (size_t)kbase[pr] + wi) = m;
        }
    } else {
        int total = nprs * tpp;
        for (int i = t; i < total; i += 256) {
            int pr = (unsigned)i / (unsigned)tpp;
            int wi = i - pr * tpp;
            mask[(size_t)kbase[pr] + wi] = (wi < kk[pr]) ? 1.0f : 0.0f;
        }
    }
}

// ---------------- pad (only if 196*tpp < num_tokens; not hit at these sizes) ----
__global__ void k_pad(float* __restrict__ mask, int B, int num_tokens, int used) {
    int per = num_tokens - used;
    int idx = blockIdx.x * 256 + threadIdx.x;
    int tot = B * per;
    if (idx < tot) {
        int b = idx / per;
        int j = idx - b * per;
        mask[(size_t)b * num_tokens + used + j] = 0.0f;
    }
}

extern "C" void kernel_launch(void* const* d_in, const int* in_sizes, int n_in,
                              void* d_out, int out_size, void* d_ws, size_t ws_size,
                              hipStream_t stream) {
    const float* motion = (const float*)d_in[0];
    int nelem = in_sizes[0];                 // B*1*224*224
    int B     = nelem / IMG2;                // 512
    int npair = B * HW2;                     // 100352
    int num_tokens = (out_size - 2 * npair) / B;   // 6272
    int tpp   = num_tokens / HW2;            // 32

    // workspace layout
    float* resized = (float*)d_ws;
    size_t off = ((size_t)npair * sizeof(float) + 7) & ~(size_t)7;
    double* psum = (double*)((char*)d_ws + off);
    float*  pmin = (float*)(psum + NBLK1);
    float*  pmax = pmin + NBLK1;

    int ngroups = (npair + 3) / 4;
    int nb1 = min(NBLK1, ngroups);
    hipLaunchKernelGGL(k_patch_mean, dim3(nb1), dim3(256), 0, stream,
                       motion, resized, pmin, pmax, psum, npair);

    int nb2 = (npair + 255) / 256;           // 392
    hipLaunchKernelGGL(k_output, dim3(nb2), dim3(256), 0, stream,
                       resized, pmin, pmax, psum, nb1,
                       (float*)d_out, npair, tpp, num_tokens);

    int used = HW2 * tpp;
    if (used < num_tokens) {
        int tot = B * (num_tokens - used);
        hipLaunchKernelGGL(k_pad, dim3((tot + 255) / 256), dim3(256), 0, stream,
                           (float*)d_out + 2 * (size_t)npair, B, num_tokens, used);
    }
}